// Round 1
// 263.925 us; speedup vs baseline: 1.0386x; 1.0386x over previous
//
#include <hip/hip_runtime.h>
#include <stdint.h>

typedef unsigned short u16;
typedef __attribute__((ext_vector_type(8))) short short8;
typedef __attribute__((ext_vector_type(4))) short s16x4;
typedef __attribute__((ext_vector_type(4))) float f32x4;
typedef __attribute__((ext_vector_type(4))) unsigned short u16x4;

#define S_LEN 2048
#define NH 16
#define DMODEL 1024
#define NR 129
#define LOG2E 1.44269504f

#define MFMA(a,b,c) __builtin_amdgcn_mfma_f32_16x16x32_bf16((a),(b),(c),0,0,0)

__device__ __forceinline__ u16 f2bf(float f){            // RTNE (for Q/K/V/emb)
  uint32_t u = __float_as_uint(f);
  u += 0x7fff + ((u >> 16) & 1);
  return (u16)(u >> 16);
}
__device__ __forceinline__ u16 f2bfa(float f){           // RTNA (cheap, for p>=0)
  return (u16)((__float_as_uint(f) + 0x8000u) >> 16);
}
__device__ __forceinline__ float bf2f(u16 h){ return __uint_as_float(((uint32_t)h) << 16); }

// ---------------- prep: convx + transw + convemb + mask*log2e, one launch ----------------
// blocks: [0,4096) convx | [4096,4864) transw | [4864,4900) convemb | [4900,4916) maskL
__global__ __launch_bounds__(256) void k_prep(const float* __restrict__ X,
                                              const float* __restrict__ Wq, const float* __restrict__ Wk,
                                              const float* __restrict__ Wv, const float* __restrict__ Wemb,
                                              const float* __restrict__ mask,
                                              u16* __restrict__ Xb, u16* __restrict__ Wt,
                                              u16* __restrict__ Eb, float* __restrict__ maskL){
  const int bid = blockIdx.x, tid = threadIdx.x;
  if (bid < 4096){
    int i = bid * 256 + tid;
    const float4* xp = (const float4*)X;
    float4 v = xp[i];
    u16x4 o; o.x = f2bf(v.x); o.y = f2bf(v.y); o.z = f2bf(v.z); o.w = f2bf(v.w);
    *(u16x4*)(Xb + (size_t)i * 4) = o;
  } else if (bid < 4864){
    int b2 = bid - 4096;
    int z = b2 >> 8;
    const float* W = (z == 0) ? Wq : (z == 1) ? Wk : Wv;
    u16* Ot = Wt + (size_t)z * 1024 * 1024;
    __shared__ float t[64][65];
    int k0 = ((b2 >> 4) & 15) * 64, n0 = (b2 & 15) * 64;
    int c = tid & 63, r0 = (tid >> 6) * 16;
    #pragma unroll
    for (int i = 0; i < 16; ++i) t[r0 + i][c] = W[(size_t)(k0 + r0 + i) * 1024 + n0 + c];
    __syncthreads();
    #pragma unroll
    for (int i = 0; i < 16; ++i) Ot[(size_t)(n0 + r0 + i) * 1024 + k0 + c] = f2bf(t[c][r0 + i]);
  } else if (bid < 4900){
    int idx = (bid - 4864) * 256 + tid;
    if (idx < 144 * 64){
      int r = idx >> 6;
      Eb[idx] = (r < NR) ? f2bf(Wemb[idx]) : (u16)0;
    }
  } else {
    int idx = (bid - 4900) * 256 + tid;   // 4096 mask elements
    maskL[idx] = mask[idx] * LOG2E;
  }
}

// ---------------- QKV GEMM: [4096,1024] x Wt[1024,1024]^T, bf16 MFMA ----------------
// out layout: [g = b*16+h][s][j] bf16 ; Q pre-scaled by 0.125*log2(e) (base-2 softmax)
__global__ __launch_bounds__(256) void k_qkv(const u16* __restrict__ Xb, const u16* __restrict__ Wt,
                                             const float* __restrict__ bq, const float* __restrict__ bk,
                                             const float* __restrict__ bv,
                                             u16* __restrict__ Qs, u16* __restrict__ Kb, u16* __restrict__ Vb){
  const int z = blockIdx.z;
  const u16* W = Wt + (size_t)z * 1024 * 1024;
  const float* bias = (z == 0) ? bq : (z == 1) ? bk : bv;
  u16* outp = (z == 0) ? Qs : (z == 1) ? Kb : Vb;
  const float vs = (z == 0) ? 0.125f * LOG2E : 1.0f;
  const int n0 = blockIdx.x * 128, m0 = blockIdx.y * 128;
  const int tid = threadIdx.x, w = tid >> 6, lane = tid & 63, l15 = lane & 15, quad = lane >> 4;
  const int wm = (w >> 1) * 64, wn = (w & 1) * 64;
  __shared__ __attribute__((aligned(16))) u16 As[128][40];
  __shared__ __attribute__((aligned(16))) u16 Bs[128][40];
  f32x4 acc[4][4];
  #pragma unroll
  for (int i = 0; i < 4; ++i)
    #pragma unroll
    for (int j = 0; j < 4; ++j) acc[i][j] = (f32x4){0.f,0.f,0.f,0.f};

  for (int k0 = 0; k0 < 1024; k0 += 32){
    __syncthreads();
    #pragma unroll
    for (int i = 0; i < 2; ++i){
      int c = tid + i * 256; int r = c >> 2, ch = (c & 3) * 8;
      *(short8*)&As[r][ch] = *(const short8*)(Xb + (size_t)(m0 + r) * 1024 + k0 + ch);
      *(short8*)&Bs[r][ch] = *(const short8*)(W  + (size_t)(n0 + r) * 1024 + k0 + ch);
    }
    __syncthreads();
    short8 af[4], bfr[4];
    #pragma unroll
    for (int f = 0; f < 4; ++f){
      af[f]  = *(const short8*)&As[wm + f * 16 + l15][quad * 8];
      bfr[f] = *(const short8*)&Bs[wn + f * 16 + l15][quad * 8];
    }
    #pragma unroll
    for (int i = 0; i < 4; ++i)
      #pragma unroll
      for (int j = 0; j < 4; ++j) acc[i][j] = MFMA(af[i], bfr[j], acc[i][j]);
  }
  #pragma unroll
  for (int i = 0; i < 4; ++i){
    #pragma unroll
    for (int j = 0; j < 4; ++j){
      int col = n0 + wn + j * 16 + l15;
      float bsv = bias[col];
      int hh = col >> 6, jd = col & 63;
      #pragma unroll
      for (int r = 0; r < 4; ++r){
        int row = m0 + wm + i * 16 + quad * 4 + r;
        int bb = row >> 11, s = row & 2047;
        float vv = (acc[i][j][r] + bsv) * vs;
        outp[(((size_t)(bb * 16 + hh)) * S_LEN + s) * 64 + jd] = f2bf(vv);
      }
    }
  }
}

// ---------------- transpose V: [g][s][d] -> Vt[g][d][s] ----------------
__global__ __launch_bounds__(256) void k_transv(const u16* __restrict__ Vb, u16* __restrict__ Vt){
  const int g = blockIdx.y; const int s0 = blockIdx.x * 64;
  __shared__ __attribute__((aligned(16))) u16 t[64][72];
  const int tid = threadIdx.x;
  #pragma unroll
  for (int i = 0; i < 2; ++i){
    int c = tid + i * 256; int r = c >> 3, ch = (c & 7) * 8;
    *(short8*)&t[r][ch] = *(const short8*)(Vb + ((size_t)g * S_LEN + s0 + r) * 64 + ch);
  }
  __syncthreads();
  #pragma unroll
  for (int i = 0; i < 2; ++i){
    int c = tid + i * 256; int d = c >> 3, ch = (c & 7) * 8;
    short8 vv;
    #pragma unroll
    for (int u = 0; u < 8; ++u) vv[u] = (short)t[ch + u][d];
    *(short8*)(Vt + ((size_t)g * 64 + d) * S_LEN + s0 + ch) = vv;
  }
}

// ---------------- fused flash + rel_v band, base-2 softmax, fixed m=0 ----------------
// SWAPPED QK^T: sc = mfma(K, Q) -> lane holds one q-row (l15), k = quad*4+r.
// P never touches LDS: packed to bf16 in regs, fed to PV mfma as A-operand.
// Vs is stored column-PERMUTED (c' = quad*16 + fn*4 + r, i.e. fn/quad bit-fields
// swapped) so one ds_read_b128 yields the matching B-operand for an fn-pair.
// l / ll / rsb are single scalars per lane (row = l15), reduced over quad bits
// and redistributed to output rows (quad*4+r) via 12 shfls at the end.
__global__ __launch_bounds__(256, 3) void k_flash(const u16* __restrict__ QS, const u16* __restrict__ KB,
                                                  const u16* __restrict__ VT, const u16* __restrict__ EMBK,
                                                  const float* __restrict__ maskL, const float* __restrict__ embv,
                                                  float* __restrict__ out){
  const int g = blockIdx.y; const int b = g >> 4; const int h = g & 15;
  const int q0 = blockIdx.x * 64;
  const int tid = threadIdx.x;
  const int w = tid >> 6; const int lane = tid & 63;
  const int l15 = lane & 15; const int quad = lane >> 4;
  const int wm = w * 16;
  const int rqb = quad * 4;
  const int qrow = q0 + wm + l15;      // this lane's q-row (swapped layout)

  __shared__ union UKE {
    struct {
      __attribute__((aligned(16))) u16 Ks[64][72];
      __attribute__((aligned(16))) u16 Vs[64][72];   // column-permuted (see above)
    } s;
    __attribute__((aligned(16))) u16 Evs[64][136];   // Evs[d][t] = emb_v[127-t][d]
  } uu;                                              // 18,432 B
  __shared__ __attribute__((aligned(16))) u16 QEb[4][16][132];  // 16,896
  __shared__ __attribute__((aligned(16))) u16 Psb[64][136];     // 17,408  (total 52,736 -> 3 blocks/CU)

  // zero Psb
  {
    short8 z8 = (short8){0,0,0,0,0,0,0,0};
    for (int i = tid; i < 64 * 136 / 8; i += 256) ((short8*)Psb)[i] = z8;
  }

  // Q fragments straight from global (rows = q, used as B in QK^T, A in qe-MFMA)
  const u16* qptr = QS + ((size_t)g * S_LEN + q0 + wm + l15) * 64 + quad * 8;
  short8 qa0 = *(const short8*)qptr;
  short8 qa1 = *(const short8*)(qptr + 32);

  // qe = Q @ emb_k^T (this wave's 16 rows; cols 0..128), bf16 into wave-private LDS
  #pragma unroll
  for (int fn = 0; fn < 9; ++fn){
    const u16* ep = EMBK + (fn * 16 + l15) * 64 + quad * 8;
    short8 eb0 = *(const short8*)ep;
    short8 eb1 = *(const short8*)(ep + 32);
    f32x4 c = (f32x4){0.f,0.f,0.f,0.f};
    c = MFMA(qa0, eb0, c);
    c = MFMA(qa1, eb1, c);
    int col = fn * 16 + l15;
    if (col < NR){
      #pragma unroll
      for (int r = 0; r < 4; ++r) QEb[w][rqb + r][col] = f2bf(c[r]);
    }
  }
  __syncthreads();   // QEb + Psb-zero visible

  const float qeR = bf2f(QEb[w][l15][0]);     // lane-constant (row = l15)
  const float qeL = bf2f(QEb[w][l15][128]);

  f32x4 o[4];
  #pragma unroll
  for (int f = 0; f < 4; ++f) o[f] = (f32x4){0.f,0.f,0.f,0.f};
  float l_sum = 0.f;      // row sum (raw), this lane's row = qrow
  float ll0   = 0.f;      // snapshot after last fully-left tile
  float ll_mx = 0.f;      // clamped-left contributions from mixed tiles
  float rsb_s = 0.f;      // band row-sum (raw)

  for (int kt = 0; kt < S_LEN; kt += 64){
    __syncthreads();
    #pragma unroll
    for (int i = 0; i < 2; ++i){
      int c = tid + i * 256; int row = c >> 3, ch = (c & 7) * 8;
      *(short8*)&uu.s.Ks[row][ch] = *(const short8*)(KB + ((size_t)g * S_LEN + kt + row) * 64 + ch);
      // V staged column-permuted: src k = ch+u -> dest c' = q*16 + f*4 + r
      short8 vsrc = *(const short8*)(VT + ((size_t)g * 64 + row) * S_LEN + kt + ch);
      int c0 = ((ch & 8) ? 32 : 0) + (ch >> 4) * 4;
      s16x4 lo = __builtin_shufflevector(vsrc, vsrc, 0, 1, 2, 3);
      s16x4 hi = __builtin_shufflevector(vsrc, vsrc, 4, 5, 6, 7);
      *(s16x4*)&uu.s.Vs[row][c0]      = lo;
      *(s16x4*)&uu.s.Vs[row][c0 + 16] = hi;
    }
    __syncthreads();

    // scores, swapped: sc[fn][r] = S[qrow][kt + fn*16 + quad*4 + r] (log2 domain)
    f32x4 sc[4];
    #pragma unroll
    for (int fn = 0; fn < 4; ++fn){
      short8 kb0 = *(const short8*)&uu.s.Ks[fn * 16 + l15][quad * 8];
      short8 kb1 = *(const short8*)&uu.s.Ks[fn * 16 + l15][32 + quad * 8];
      f32x4 c = (f32x4){0.f,0.f,0.f,0.f};
      c = MFMA(kb0, qa0, c);
      c = MFMA(kb1, qa1, c);
      sc[fn] = c;
    }

    if (kt <= q0 - 128){
      // fully left-clamped: ridx=128 (qe lane-constant, folded into mask vec)
      #pragma unroll
      for (int fn = 0; fn < 4; ++fn){
        f32x4 mv = *(const f32x4*)&maskL[b * S_LEN + kt + fn * 16 + rqb];
        mv += qeL;
        #pragma unroll
        for (int r = 0; r < 4; ++r){
          float p = exp2f(sc[fn][r] + mv[r]);
          l_sum += p;
          sc[fn][r] = p;
        }
      }
    } else if (kt >= q0 + 128){
      // fully right-clamped: ridx=0
      #pragma unroll
      for (int fn = 0; fn < 4; ++fn){
        f32x4 mv = *(const f32x4*)&maskL[b * S_LEN + kt + fn * 16 + rqb];
        mv += qeR;
        #pragma unroll
        for (int r = 0; r < 4; ++r){
          float p = exp2f(sc[fn][r] + mv[r]);
          l_sum += p;
          sc[fn][r] = p;
        }
      }
    } else {
      // mixed: per-element gather + band capture
      #pragma unroll
      for (int fn = 0; fn < 4; ++fn){
        f32x4 mv = *(const f32x4*)&maskL[b * S_LEN + kt + fn * 16 + rqb];
        int kbase = kt + fn * 16 + rqb;
        #pragma unroll
        for (int r = 0; r < 4; ++r){
          int dq = qrow - (kbase + r) + 64;     // unclamped rel idx
          int ridx = min(max(dq, 0), 128);
          float p = exp2f(sc[fn][r] + bf2f(QEb[w][l15][ridx]) + mv[r]);
          l_sum += p;
          ll_mx += (dq >= 128) ? p : 0.f;
          if (dq >= 1 && dq <= 127){            // band element: t = 127 - dq
            Psb[wm + l15][127 - dq] = f2bfa(p);
            rsb_s += p;
          }
          sc[fn][r] = p;
        }
      }
    }

    // PV straight from registers: fn-pair fp packs into one A-operand;
    // matching B-operand is one b128 from permuted Vs.
    #pragma unroll
    for (int fp = 0; fp < 2; ++fp){
      short8 pa;
      #pragma unroll
      for (int r = 0; r < 4; ++r){
        pa[r]     = (short)f2bfa(sc[2 * fp][r]);
        pa[4 + r] = (short)f2bfa(sc[2 * fp + 1][r]);
      }
      #pragma unroll
      for (int fd = 0; fd < 4; ++fd){
        short8 vb = *(const short8*)&uu.s.Vs[fd * 16 + l15][quad * 16 + fp * 8];
        o[fd] = MFMA(pa, vb, o[fd]);
      }
    }

    if (kt == q0 - 128) ll0 = l_sum;
  }

  // ---- band tail ----
  __syncthreads();   // all Ks/Vs reads done; Psb writes complete
  // build Evs in the union region: Evs[d][t] = emb_v[127-t][d] (t<=126), else 0
  {
    int d = tid & 63, t4 = tid >> 6;
    #pragma unroll
    for (int it = 0; it < 34; ++it){
      int t = t4 + it * 4;
      float v = (t <= 126) ? embv[(size_t)(127 - t) * 64 + d] : 0.f;
      uu.Evs[d][t] = f2bf(v);
    }
  }
  __syncthreads();

  f32x4 ob[4];
  #pragma unroll
  for (int f = 0; f < 4; ++f) ob[f] = (f32x4){0.f,0.f,0.f,0.f};
  #pragma unroll
  for (int kb = 0; kb < 4; ++kb){
    short8 pa = *(const short8*)&Psb[wm + l15][kb * 32 + quad * 8];
    #pragma unroll
    for (int fd = 0; fd < 4; ++fd){
      short8 vb = *(const short8*)&uu.Evs[fd * 16 + l15][kb * 32 + quad * 8];
      ob[fd] = MFMA(pa, vb, ob[fd]);
    }
  }

  // final reductions: sums live per-lane for row l15; reduce over quad bits,
  // then redistribute to this lane's output rows (quad*4+r) via shfl.
  float llv = ll0 + ll_mx;
  #pragma unroll
  for (int st = 16; st < 64; st <<= 1){
    l_sum += __shfl_xor(l_sum, st, 64);
    llv   += __shfl_xor(llv,   st, 64);
    rsb_s += __shfl_xor(rsb_s, st, 64);
  }

  float inv[4], tl[4], trr[4];
  #pragma unroll
  for (int r = 0; r < 4; ++r){
    int src = (quad << 4) + rqb + r;   // lane with l15 = quad*4+r, same quad
    float L  = __shfl(l_sum, src, 64);
    float lv = __shfl(llv,   src, 64);
    float rv = __shfl(rsb_s, src, 64);
    inv[r] = 1.f / L;
    tl[r]  = lv * inv[r];
    trr[r] = 1.f - tl[r] - rv * inv[r];
  }

  #pragma unroll
  for (int fd = 0; fd < 4; ++fd){
    int dim = fd * 16 + l15;
    float evL = embv[(size_t)128 * 64 + dim];   // ridx=128 (k <= q-64)
    float evR = embv[dim];                      // ridx=0   (k >= q+64)
    #pragma unroll
    for (int r = 0; r < 4; ++r){
      int row = q0 + wm + rqb + r;
      float val = (o[fd][r] + ob[fd][r]) * inv[r] + tl[r] * evL + trr[r] * evR;
      out[((size_t)(b * S_LEN + row)) * DMODEL + h * 64 + dim] = val;
    }
  }
}

extern "C" void kernel_launch(void* const* d_in, const int* in_sizes, int n_in,
                              void* d_out, int out_size, void* d_ws, size_t ws_size,
                              hipStream_t stream){
  const float* X    = (const float*)d_in[0];
  const float* mask = (const float*)d_in[1];
  const float* Wq   = (const float*)d_in[2];
  const float* bq   = (const float*)d_in[3];
  const float* Wk   = (const float*)d_in[4];
  const float* bk   = (const float*)d_in[5];
  const float* Wv   = (const float*)d_in[6];
  const float* bv   = (const float*)d_in[7];
  const float* embk = (const float*)d_in[8];
  const float* embv = (const float*)d_in[9];
  float* out = (float*)d_out;
  char* ws = (char*)d_ws;

  u16* XB   = (u16*)(ws + 0);            // 8,388,608
  u16* WT   = (u16*)(ws + 8388608);      // 6,291,456
  u16* EKB  = (u16*)(ws + 14680064);     // 18,432
  u16* QS   = (u16*)(ws + 14698496);     // 8,388,608
  u16* KB   = (u16*)(ws + 23087104);     // 8,388,608
  u16* VB   = (u16*)(ws + 31475712);     // 8,388,608
  u16* VT   = (u16*)(ws + 39864320);     // 8,388,608
  float* MSL = (float*)(ws + 48252928);  // 16,384  (end 48,269,312)

  k_prep   <<<4916, 256, 0, stream>>>(X, Wq, Wk, Wv, embk, mask, XB, WT, EKB, MSL);
  k_qkv    <<<dim3(8, 32, 3), 256, 0, stream>>>(XB, WT, bq, bk, bv, QS, KB, VB);
  k_transv <<<dim3(32, 32), 256, 0, stream>>>(VB, VT);
  k_flash  <<<dim3(32, 32), 256, 0, stream>>>(QS, KB, VT, EKB, MSL, embv, out);
}

// Round 2
// 213.806 us; speedup vs baseline: 1.2820x; 1.2344x over previous
//
#include <hip/hip_runtime.h>
#include <stdint.h>

typedef unsigned short u16;
typedef __attribute__((ext_vector_type(8))) short short8;
typedef __attribute__((ext_vector_type(4))) short s16x4;
typedef __attribute__((ext_vector_type(4))) float f32x4;
typedef __attribute__((ext_vector_type(4))) unsigned short u16x4;

#define S_LEN 2048
#define NH 16
#define DMODEL 1024
#define NR 129
#define LOG2E 1.44269504f

#define MFMA(a,b,c) __builtin_amdgcn_mfma_f32_16x16x32_bf16((a),(b),(c),0,0,0)

__device__ __forceinline__ u16 f2bf(float f){            // RTNE (for Q/K/V/emb)
  uint32_t u = __float_as_uint(f);
  u += 0x7fff + ((u >> 16) & 1);
  return (u16)(u >> 16);
}
__device__ __forceinline__ u16 f2bfa(float f){           // RTNA (cheap, for p>=0)
  return (u16)((__float_as_uint(f) + 0x8000u) >> 16);
}
__device__ __forceinline__ float bf2f(u16 h){ return __uint_as_float(((uint32_t)h) << 16); }

// packed f32x2 -> bf16x2 (RTNE), single VALU op
__device__ __forceinline__ uint32_t cvtpk(float lo, float hi){
  uint32_t r;
  asm("v_cvt_pk_bf16_f32 %0, %1, %2" : "=v"(r) : "v"(lo), "v"(hi));
  return r;
}

// async global->LDS, 16B per lane; lds dest must be wave-uniform base (+lane*16 by HW)
__device__ __forceinline__ void gl_lds16(const u16* g, u16* l){
  __builtin_amdgcn_global_load_lds((const __attribute__((address_space(1))) void*)g,
                                   (__attribute__((address_space(3))) void*)l, 16, 0, 0);
}

// ---------------- prep: convx + transw + convemb + mask*log2e, one launch ----------------
// blocks: [0,4096) convx | [4096,4864) transw | [4864,4900) convemb | [4900,4916) maskL
__global__ __launch_bounds__(256) void k_prep(const float* __restrict__ X,
                                              const float* __restrict__ Wq, const float* __restrict__ Wk,
                                              const float* __restrict__ Wv, const float* __restrict__ Wemb,
                                              const float* __restrict__ mask,
                                              u16* __restrict__ Xb, u16* __restrict__ Wt,
                                              u16* __restrict__ Eb, float* __restrict__ maskL){
  const int bid = blockIdx.x, tid = threadIdx.x;
  if (bid < 4096){
    int i = bid * 256 + tid;
    const float4* xp = (const float4*)X;
    float4 v = xp[i];
    u16x4 o; o.x = f2bf(v.x); o.y = f2bf(v.y); o.z = f2bf(v.z); o.w = f2bf(v.w);
    *(u16x4*)(Xb + (size_t)i * 4) = o;
  } else if (bid < 4864){
    int b2 = bid - 4096;
    int z = b2 >> 8;
    const float* W = (z == 0) ? Wq : (z == 1) ? Wk : Wv;
    u16* Ot = Wt + (size_t)z * 1024 * 1024;
    __shared__ float t[64][65];
    int k0 = ((b2 >> 4) & 15) * 64, n0 = (b2 & 15) * 64;
    int c = tid & 63, r0 = (tid >> 6) * 16;
    #pragma unroll
    for (int i = 0; i < 16; ++i) t[r0 + i][c] = W[(size_t)(k0 + r0 + i) * 1024 + n0 + c];
    __syncthreads();
    #pragma unroll
    for (int i = 0; i < 16; ++i) Ot[(size_t)(n0 + r0 + i) * 1024 + k0 + c] = f2bf(t[c][r0 + i]);
  } else if (bid < 4900){
    int idx = (bid - 4864) * 256 + tid;
    if (idx < 144 * 64){
      int r = idx >> 6;
      Eb[idx] = (r < NR) ? f2bf(Wemb[idx]) : (u16)0;
    }
  } else {
    int idx = (bid - 4900) * 256 + tid;   // 4096 mask elements
    maskL[idx] = mask[idx] * LOG2E;
  }
}

// ---------------- QKV GEMM: [4096,1024] x Wt[1024,1024]^T, bf16 MFMA, m97 structure ----------------
// global_load_lds width-16 into LINEAR [128][32] tiles (conflict-free frag reads).
// out layout: [g = b*16+h][s][j] bf16 ; Q pre-scaled by 0.125*log2(e) (base-2 softmax)
__global__ __launch_bounds__(256) void k_qkv(const u16* __restrict__ Xb, const u16* __restrict__ Wt,
                                             const float* __restrict__ bq, const float* __restrict__ bk,
                                             const float* __restrict__ bv,
                                             u16* __restrict__ Qs, u16* __restrict__ Kb, u16* __restrict__ Vb){
  const int z = blockIdx.z;
  const u16* W = Wt + (size_t)z * 1024 * 1024;
  const float* bias = (z == 0) ? bq : (z == 1) ? bk : bv;
  u16* outp = (z == 0) ? Qs : (z == 1) ? Kb : Vb;
  const float vs = (z == 0) ? 0.125f * LOG2E : 1.0f;
  const int n0 = blockIdx.x * 128, m0 = blockIdx.y * 128;
  const int tid = threadIdx.x, w = tid >> 6, lane = tid & 63, l15 = lane & 15, quad = lane >> 4;
  const int wm = (w >> 1) * 64, wn = (w & 1) * 64;
  __shared__ __attribute__((aligned(16))) u16 As[128 * 32];
  __shared__ __attribute__((aligned(16))) u16 Bs[128 * 32];
  f32x4 acc[4][4];
  #pragma unroll
  for (int i = 0; i < 4; ++i)
    #pragma unroll
    for (int j = 0; j < 4; ++j) acc[i][j] = (f32x4){0.f,0.f,0.f,0.f};

  // staging coords: wave w writes rows [w*16, w*16+16) of each 64-row half; lane covers
  // row = (lane>>2), 16B chunk = (lane&3)
  const int rA = lane >> 2, cA = (lane & 3) * 8;
  const u16* aBase = Xb + (size_t)(m0 + w * 16 + rA) * 1024 + cA;
  const u16* bBase = W  + (size_t)(n0 + w * 16 + rA) * 1024 + cA;
  u16* aDst0 = As + (w * 16) * 32;  u16* aDst1 = As + (64 + w * 16) * 32;
  u16* bDst0 = Bs + (w * 16) * 32;  u16* bDst1 = Bs + (64 + w * 16) * 32;

  for (int k0 = 0; k0 < 1024; k0 += 32){
    __syncthreads();
    gl_lds16(aBase + k0,             aDst0);
    gl_lds16(aBase + 64 * 1024 + k0, aDst1);
    gl_lds16(bBase + k0,             bDst0);
    gl_lds16(bBase + 64 * 1024 + k0, bDst1);
    __syncthreads();
    short8 af[4], bfr[4];
    #pragma unroll
    for (int f = 0; f < 4; ++f){
      af[f]  = *(const short8*)(As + (wm + f * 16 + l15) * 32 + quad * 8);
      bfr[f] = *(const short8*)(Bs + (wn + f * 16 + l15) * 32 + quad * 8);
    }
    #pragma unroll
    for (int i = 0; i < 4; ++i)
      #pragma unroll
      for (int j = 0; j < 4; ++j) acc[i][j] = MFMA(af[i], bfr[j], acc[i][j]);
  }
  #pragma unroll
  for (int i = 0; i < 4; ++i){
    #pragma unroll
    for (int j = 0; j < 4; ++j){
      int col = n0 + wn + j * 16 + l15;
      float bsv = bias[col];
      int hh = col >> 6, jd = col & 63;
      #pragma unroll
      for (int r = 0; r < 4; ++r){
        int row = m0 + wm + i * 16 + quad * 4 + r;
        int bb = row >> 11, s = row & 2047;
        float vv = (acc[i][j][r] + bsv) * vs;
        outp[(((size_t)(bb * 16 + hh)) * S_LEN + s) * 64 + jd] = f2bf(vv);
      }
    }
  }
}

// ---------------- transpose V: [g][s][d] -> Vt[g][d][s] ----------------
__global__ __launch_bounds__(256) void k_transv(const u16* __restrict__ Vb, u16* __restrict__ Vt){
  const int g = blockIdx.y; const int s0 = blockIdx.x * 64;
  __shared__ __attribute__((aligned(16))) u16 t[64][72];
  const int tid = threadIdx.x;
  #pragma unroll
  for (int i = 0; i < 2; ++i){
    int c = tid + i * 256; int r = c >> 3, ch = (c & 7) * 8;
    *(short8*)&t[r][ch] = *(const short8*)(Vb + ((size_t)g * S_LEN + s0 + r) * 64 + ch);
  }
  __syncthreads();
  #pragma unroll
  for (int i = 0; i < 2; ++i){
    int c = tid + i * 256; int d = c >> 3, ch = (c & 7) * 8;
    short8 vv;
    #pragma unroll
    for (int u = 0; u < 8; ++u) vv[u] = (short)t[ch + u][d];
    *(short8*)(Vt + ((size_t)g * 64 + d) * S_LEN + s0 + ch) = vv;
  }
}

// ---------------- fused flash + rel_v band, base-2 softmax, fixed m=0 ----------------
// Swapped QK^T (lane = one q-row). This round:
//  - T14 async-stage: K/V/mask for tile kt+1 loaded to regs during tile kt compute
//  - mask+qe folded into QK MFMA C-init (clamped tiles)
//  - raw v_exp_f32 (scores bounded), v_cvt_pk_bf16_f32 for P pack
//  - row-sum l via MFMA against ones-column B fragment (no VALU adds, no quad reduce)
//  - s_setprio(1) around MFMA clusters
__global__ __launch_bounds__(256, 3) void k_flash(const u16* __restrict__ QS, const u16* __restrict__ KB,
                                                  const u16* __restrict__ VT, const u16* __restrict__ EMBK,
                                                  const float* __restrict__ maskL, const float* __restrict__ embv,
                                                  float* __restrict__ out){
  const int g = blockIdx.y; const int b = g >> 4; const int h = g & 15;
  const int q0 = blockIdx.x * 64;
  const int tid = threadIdx.x;
  const int w = tid >> 6; const int lane = tid & 63;
  const int l15 = lane & 15; const int quad = lane >> 4;
  const int wm = w * 16;
  const int rqb = quad * 4;
  const int qrow = q0 + wm + l15;      // this lane's q-row (swapped layout)

  __shared__ union UKE {
    struct {
      __attribute__((aligned(16))) u16 Ks[64][72];
      __attribute__((aligned(16))) u16 Vs[64][72];   // column-permuted (c' = quad*16 + fn*4 + r)
    } s;
    __attribute__((aligned(16))) u16 Evs[64][136];   // Evs[d][t] = emb_v[127-t][d]
  } uu;                                              // 18,432 B
  __shared__ __attribute__((aligned(16))) u16 QEb[4][16][132];  // 16,896
  __shared__ __attribute__((aligned(16))) u16 Psb[64][136];     // 17,408  (total 52,736 -> 3 blocks/CU)

  // zero Psb
  {
    short8 z8 = (short8){0,0,0,0,0,0,0,0};
    for (int i = tid; i < 64 * 136 / 8; i += 256) ((short8*)Psb)[i] = z8;
  }

  // staging thread coords (same for both halves; +256 threads => +32 rows)
  const int srow0 = tid >> 3;
  const int srow1 = srow0 + 32;
  const int sch = (tid & 7) * 8;
  const int c0 = ((sch & 8) ? 32 : 0) + (sch >> 4) * 4;   // permuted dest base for V
  const u16* kSrc = KB + (size_t)g * S_LEN * 64 + sch;    // + (kt+row)*64
  const u16* vSrc = VT + (size_t)g * 64 * S_LEN + sch;    // + row*S + kt  (sch is k-offset here)
  const float* mBase = maskL + b * S_LEN;

  // prologue: issue tile-0 loads into regs (overlap with qe-MFMA section below)
  short8 kr0 = *(const short8*)(kSrc + (size_t)srow0 * 64);
  short8 kr1 = *(const short8*)(kSrc + (size_t)srow1 * 64);
  short8 vr0 = *(const short8*)(vSrc + (size_t)srow0 * S_LEN);
  short8 vr1 = *(const short8*)(vSrc + (size_t)srow1 * S_LEN);
  f32x4 mcur[4];
  #pragma unroll
  for (int fn = 0; fn < 4; ++fn) mcur[fn] = *(const f32x4*)(mBase + fn * 16 + rqb);

  // Q fragments straight from global (rows = q; B-operand in QK^T, A in qe-MFMA)
  const u16* qptr = QS + ((size_t)g * S_LEN + q0 + wm + l15) * 64 + quad * 8;
  short8 qa0 = *(const short8*)qptr;
  short8 qa1 = *(const short8*)(qptr + 32);

  // qe = Q @ emb_k^T (this wave's 16 rows; cols 0..128), bf16 into wave-private LDS
  #pragma unroll
  for (int fn = 0; fn < 9; ++fn){
    const u16* ep = EMBK + (fn * 16 + l15) * 64 + quad * 8;
    short8 eb0 = *(const short8*)ep;
    short8 eb1 = *(const short8*)(ep + 32);
    f32x4 c = (f32x4){0.f,0.f,0.f,0.f};
    c = MFMA(qa0, eb0, c);
    c = MFMA(qa1, eb1, c);
    int col = fn * 16 + l15;
    if (col < NR){
      #pragma unroll
      for (int r = 0; r < 4; ++r) QEb[w][rqb + r][col] = f2bf(c[r]);
    }
  }
  __syncthreads();   // QEb + Psb-zero visible

  const float qeR = bf2f(QEb[w][l15][0]);     // lane-constant (row = l15)
  const float qeL = bf2f(QEb[w][l15][128]);

  // ones-column B fragment for MFMA row-sums: B[col=0][k]=1, else 0
  short8 bones;
  {
    short one = (l15 == 0) ? (short)0x3F80 : (short)0;
    #pragma unroll
    for (int j = 0; j < 8; ++j) bones[j] = one;
  }

  f32x4 o[4];
  #pragma unroll
  for (int f = 0; f < 4; ++f) o[f] = (f32x4){0.f,0.f,0.f,0.f};
  f32x4 lacc = (f32x4){0.f,0.f,0.f,0.f};   // row sums, valid in l15==0 lanes (col 0)
  float ll0v[4] = {0.f,0.f,0.f,0.f};        // lacc snapshot after last fully-left tile
  float ll_mx = 0.f;                        // clamped-left contributions from mixed tiles (row = l15)
  float rsb_s = 0.f;                        // band row-sum (raw, row = l15)

  for (int kt = 0; kt < S_LEN; kt += 64){
    __syncthreads();                        // prev tile reads done
    // write staged regs -> LDS (K linear, V column-permuted)
    *(short8*)&uu.s.Ks[srow0][sch] = kr0;
    *(short8*)&uu.s.Ks[srow1][sch] = kr1;
    {
      s16x4 lo = __builtin_shufflevector(vr0, vr0, 0, 1, 2, 3);
      s16x4 hi = __builtin_shufflevector(vr0, vr0, 4, 5, 6, 7);
      *(s16x4*)&uu.s.Vs[srow0][c0]      = lo;
      *(s16x4*)&uu.s.Vs[srow0][c0 + 16] = hi;
    }
    {
      s16x4 lo = __builtin_shufflevector(vr1, vr1, 0, 1, 2, 3);
      s16x4 hi = __builtin_shufflevector(vr1, vr1, 4, 5, 6, 7);
      *(s16x4*)&uu.s.Vs[srow1][c0]      = lo;
      *(s16x4*)&uu.s.Vs[srow1][c0 + 16] = hi;
    }
    __syncthreads();

    // issue next-tile loads NOW; they complete during this tile's compute (T14)
    const int ktn = kt + 64;
    f32x4 mnext[4];
    if (ktn < S_LEN){
      kr0 = *(const short8*)(kSrc + (size_t)(ktn + srow0) * 64);
      kr1 = *(const short8*)(kSrc + (size_t)(ktn + srow1) * 64);
      vr0 = *(const short8*)(vSrc + (size_t)srow0 * S_LEN + ktn);
      vr1 = *(const short8*)(vSrc + (size_t)srow1 * S_LEN + ktn);
      #pragma unroll
      for (int fn = 0; fn < 4; ++fn) mnext[fn] = *(const f32x4*)(mBase + ktn + fn * 16 + rqb);
    }

    const bool leftC  = (kt <= q0 - 128);
    const bool rightC = (kt >= q0 + 128);
    const float qeadd = leftC ? qeL : (rightC ? qeR : 0.f);

    // scores: C-init = mask(+qe); sc[fn][r] = S[k = kt+fn*16+quad*4+r][q = qrow] + mask + qe
    f32x4 p4[4];
    __builtin_amdgcn_s_setprio(1);
    #pragma unroll
    for (int fn = 0; fn < 4; ++fn){
      short8 kb0 = *(const short8*)&uu.s.Ks[fn * 16 + l15][quad * 8];
      short8 kb1 = *(const short8*)&uu.s.Ks[fn * 16 + l15][32 + quad * 8];
      f32x4 c = mcur[fn] + qeadd;
      c = MFMA(kb0, qa0, c);
      c = MFMA(kb1, qa1, c);
      p4[fn] = c;
    }
    __builtin_amdgcn_s_setprio(0);

    if (leftC | rightC){
      #pragma unroll
      for (int fn = 0; fn < 4; ++fn)
        #pragma unroll
        for (int r = 0; r < 4; ++r) p4[fn][r] = __builtin_amdgcn_exp2f(p4[fn][r]);
    } else {
      // mixed: per-element qe gather + band capture
      #pragma unroll
      for (int fn = 0; fn < 4; ++fn){
        int kbase = kt + fn * 16 + rqb;
        #pragma unroll
        for (int r = 0; r < 4; ++r){
          int dq = qrow - (kbase + r) + 64;     // unclamped rel idx
          int ridx = min(max(dq, 0), 128);
          float p = __builtin_amdgcn_exp2f(p4[fn][r] + bf2f(QEb[w][l15][ridx]));
          ll_mx += (dq >= 128) ? p : 0.f;
          if (dq >= 1 && dq <= 127){            // band element: t = 127 - dq
            Psb[wm + l15][127 - dq] = f2bfa(p);
            rsb_s += p;
          }
          p4[fn][r] = p;
        }
      }
    }

    // pack P (cvt_pk), MFMA row-sum, PV
    __builtin_amdgcn_s_setprio(1);
    #pragma unroll
    for (int fp = 0; fp < 2; ++fp){
      union { uint32_t u[4]; short8 s8; } pk;
      pk.u[0] = cvtpk(p4[2 * fp][0],     p4[2 * fp][1]);
      pk.u[1] = cvtpk(p4[2 * fp][2],     p4[2 * fp][3]);
      pk.u[2] = cvtpk(p4[2 * fp + 1][0], p4[2 * fp + 1][1]);
      pk.u[3] = cvtpk(p4[2 * fp + 1][2], p4[2 * fp + 1][3]);
      short8 pa = pk.s8;
      lacc = MFMA(pa, bones, lacc);
      #pragma unroll
      for (int fd = 0; fd < 4; ++fd){
        short8 vb = *(const short8*)&uu.s.Vs[fd * 16 + l15][quad * 16 + fp * 8];
        o[fd] = MFMA(pa, vb, o[fd]);
      }
    }
    __builtin_amdgcn_s_setprio(0);

    if (kt == q0 - 128){
      #pragma unroll
      for (int r = 0; r < 4; ++r) ll0v[r] = lacc[r];
    }
    if (ktn < S_LEN){
      #pragma unroll
      for (int fn = 0; fn < 4; ++fn) mcur[fn] = mnext[fn];
    }
  }

  // ---- band tail ----
  __syncthreads();   // all Ks/Vs reads done; Psb writes complete
  // build Evs in the union region: Evs[d][t] = emb_v[127-t][d] (t<=126), else 0
  {
    int d = tid & 63, t4 = tid >> 6;
    #pragma unroll
    for (int it = 0; it < 34; ++it){
      int t = t4 + it * 4;
      float v = (t <= 126) ? embv[(size_t)(127 - t) * 64 + d] : 0.f;
      uu.Evs[d][t] = f2bf(v);
    }
  }
  __syncthreads();

  f32x4 ob[4];
  #pragma unroll
  for (int f = 0; f < 4; ++f) ob[f] = (f32x4){0.f,0.f,0.f,0.f};
  #pragma unroll
  for (int kb = 0; kb < 4; ++kb){
    short8 pa = *(const short8*)&Psb[wm + l15][kb * 32 + quad * 8];
    #pragma unroll
    for (int fd = 0; fd < 4; ++fd){
      short8 vb = *(const short8*)&uu.Evs[fd * 16 + l15][kb * 32 + quad * 8];
      ob[fd] = MFMA(pa, vb, ob[fd]);
    }
  }

  // final reductions:
  //  - lacc / ll0v: already full sums (MFMA summed over all k); live in l15==0 lanes,
  //    indexed by (quad, reg r) -> row = quad*4 + r. Fetch via shfl from lane quad*16.
  //  - ll_mx / rsb_s: per-lane by row = l15; reduce over quads then shfl from lane
  //    with l15 = rqb + r.
  #pragma unroll
  for (int st = 16; st < 64; st <<= 1){
    ll_mx += __shfl_xor(ll_mx, st, 64);
    rsb_s += __shfl_xor(rsb_s, st, 64);
  }

  float inv[4], tl[4], trr[4];
  #pragma unroll
  for (int r = 0; r < 4; ++r){
    float L   = __shfl(lacc[r], quad << 4);
    float l0  = __shfl(ll0v[r], quad << 4);
    int src   = (quad << 4) + rqb + r;
    float lmx = __shfl(ll_mx, src);
    float rv  = __shfl(rsb_s, src);
    inv[r] = 1.f / L;
    tl[r]  = (l0 + lmx) * inv[r];
    trr[r] = 1.f - tl[r] - rv * inv[r];
  }

  #pragma unroll
  for (int fd = 0; fd < 4; ++fd){
    int dim = fd * 16 + l15;
    float evL = embv[(size_t)128 * 64 + dim];   // ridx=128 (k <= q-64)
    float evR = embv[dim];                      // ridx=0   (k >= q+64)
    #pragma unroll
    for (int r = 0; r < 4; ++r){
      int row = q0 + wm + rqb + r;
      float val = (o[fd][r] + ob[fd][r]) * inv[r] + tl[r] * evL + trr[r] * evR;
      out[((size_t)(b * S_LEN + row)) * DMODEL + h * 64 + dim] = val;
    }
  }
}

extern "C" void kernel_launch(void* const* d_in, const int* in_sizes, int n_in,
                              void* d_out, int out_size, void* d_ws, size_t ws_size,
                              hipStream_t stream){
  const float* X    = (const float*)d_in[0];
  const float* mask = (const float*)d_in[1];
  const float* Wq   = (const float*)d_in[2];
  const float* bq   = (const float*)d_in[3];
  const float* Wk   = (const float*)d_in[4];
  const float* bk   = (const float*)d_in[5];
  const float* Wv   = (const float*)d_in[6];
  const float* bv   = (const float*)d_in[7];
  const float* embk = (const float*)d_in[8];
  const float* embv = (const float*)d_in[9];
  float* out = (float*)d_out;
  char* ws = (char*)d_ws;

  u16* XB   = (u16*)(ws + 0);            // 8,388,608
  u16* WT   = (u16*)(ws + 8388608);      // 6,291,456
  u16* EKB  = (u16*)(ws + 14680064);     // 18,432
  u16* QS   = (u16*)(ws + 14698496);     // 8,388,608
  u16* KB   = (u16*)(ws + 23087104);     // 8,388,608
  u16* VB   = (u16*)(ws + 31475712);     // 8,388,608
  u16* VT   = (u16*)(ws + 39864320);     // 8,388,608
  float* MSL = (float*)(ws + 48252928);  // 16,384  (end 48,269,312)

  k_prep   <<<4916, 256, 0, stream>>>(X, Wq, Wk, Wv, embk, mask, XB, WT, EKB, MSL);
  k_qkv    <<<dim3(8, 32, 3), 256, 0, stream>>>(XB, WT, bq, bk, bv, QS, KB, VB);
  k_transv <<<dim3(32, 32), 256, 0, stream>>>(VB, VT);
  k_flash  <<<dim3(32, 32), 256, 0, stream>>>(QS, KB, VT, EKB, MSL, embv, out);
}